// Round 8
// baseline (608.337 us; speedup 1.0000x reference)
//
#include <hip/hip_runtime.h>
#include <hip/hip_fp16.h>

#define NN 100000      // nodes
#define NE 1600000     // edges
#define F0 512         // NFEAT
#define F1 128         // NHID
#define F2 64          // NCLASS

typedef short bf16x8 __attribute__((ext_vector_type(8)));
typedef float f32x4  __attribute__((ext_vector_type(4)));
typedef float f32x2  __attribute__((ext_vector_type(2)));

// fp32 -> bf16 (round-to-nearest-even, finite inputs)
static __device__ __forceinline__ unsigned short f2bf(float f) {
    unsigned int u = __float_as_uint(f);
    return (unsigned short)((u + 0x7FFFu + ((u >> 16) & 1u)) >> 16);
}

// fp32 -> fp16 bits (RNE)
static __device__ __forceinline__ unsigned short f2h(float f) {
    __half h = __float2half(f);
    return *(unsigned short*)&h;
}

// packed 2xfp16 -> 2xfp32
static __device__ __forceinline__ float2 h2f2(unsigned int u) {
    __half2 h = *(__half2*)&u;
    return __half22float2(h);
}

// ---------------------------------------------------------------------------
// Weights transpose+convert AND cnt zeroing in one launch (391 blocks).
// ---------------------------------------------------------------------------
__global__ __launch_bounds__(256)
void wt_kernel(const float* __restrict__ W1, const float* __restrict__ W2,
               unsigned short* __restrict__ W1t, unsigned short* __restrict__ W2t,
               int* __restrict__ cnt, int grid_threads)
{
    int i = blockIdx.x * 256 + threadIdx.x;
    if (i < F0 * F1) {
        int n = i / F0, k = i % F0;
        W1t[i] = f2bf(W1[k * F1 + n]);
    } else {
        int j = i - F0 * F1;
        if (j < F1 * F2) {
            int n = j / F1, k = j % F1;
            W2t[j] = f2bf(W2[k * F2 + n]);
        }
    }
    for (int z = i; z < NN + 256; z += grid_threads) cnt[z] = 0;
}

// ---------------------------------------------------------------------------
// Shared GEMM tile body (bf16 MFMA; A fp32 converted on the fly; Bt[N,K] bf16;
// C fp16). Caller provides the LDS buffers.
// ---------------------------------------------------------------------------
template<int BM, int BN, int BK, int TN>
static __device__ __forceinline__
void gemm_tile(unsigned short* As, unsigned short* Bs,
               const float* __restrict__ A, const unsigned short* __restrict__ Bt,
               unsigned short* __restrict__ C, int M, int K, int N, int row0)
{
    constexpr int LDA = BK + 8;   // pad: 72 shorts = 144 B = 36 banks
    constexpr int LDB = BK + 8;

    const int tid  = threadIdx.x;
    const int wave = tid >> 6;
    const int lane = tid & 63;
    const int lr   = lane & 15;
    const int quad = lane >> 4;

    f32x4 acc[2][TN];
#pragma unroll
    for (int i = 0; i < 2; i++)
#pragma unroll
        for (int j = 0; j < TN; j++) acc[i][j] = (f32x4)0.f;

    for (int k0 = 0; k0 < K; k0 += BK) {
        // --- stage A tile (BM x BK) fp32 -> bf16 ---
#pragma unroll
        for (int l = tid; l < BM * (BK / 4); l += 256) {
            int m  = l / (BK / 4);
            int kq = l % (BK / 4);
            int rg = row0 + m; if (rg >= M) rg = M - 1;
            float4 v = *(const float4*)(A + (long long)rg * K + k0 + kq * 4);
            ushort4 b = make_ushort4(f2bf(v.x), f2bf(v.y), f2bf(v.z), f2bf(v.w));
            *(ushort4*)(&As[m * LDA + kq * 4]) = b;
        }
        // --- stage B tile (BN x BK) from Bt[N,K] (already bf16) ---
#pragma unroll
        for (int l = tid; l < BN * (BK / 8); l += 256) {
            int n  = l / (BK / 8);
            int ko = l % (BK / 8);
            uint4 v = *(const uint4*)(Bt + (long long)n * K + k0 + ko * 8);
            *(uint4*)(&Bs[n * LDB + ko * 8]) = v;
        }
        __syncthreads();

#pragma unroll
        for (int kk = 0; kk < BK; kk += 32) {
            bf16x8 a[2], b[TN];
#pragma unroll
            for (int tm = 0; tm < 2; tm++)
                a[tm] = *(const bf16x8*)(&As[(wave * 32 + tm * 16 + lr) * LDA + kk + quad * 8]);
#pragma unroll
            for (int tn = 0; tn < TN; tn++)
                b[tn] = *(const bf16x8*)(&Bs[(tn * 16 + lr) * LDB + kk + quad * 8]);
#pragma unroll
            for (int tm = 0; tm < 2; tm++)
#pragma unroll
                for (int tn = 0; tn < TN; tn++)
                    acc[tm][tn] = __builtin_amdgcn_mfma_f32_16x16x32_bf16(
                        a[tm], b[tn], acc[tm][tn], 0, 0, 0);
        }
        __syncthreads();
    }

    // --- epilogue: C/D layout col=lane&15, row=quad*4+reg; store fp16 ---
#pragma unroll
    for (int tm = 0; tm < 2; tm++) {
#pragma unroll
        for (int r = 0; r < 4; r++) {
            int row = row0 + wave * 32 + tm * 16 + quad * 4 + r;
            if (row < M) {
#pragma unroll
                for (int tn = 0; tn < TN; tn++)
                    C[(long long)row * N + tn * 16 + lr] = f2h(acc[tm][tn][r]);
            }
        }
    }
}

// ---------------------------------------------------------------------------
// Merged dispatch: blocks [0, gemm_blocks) run a GEMM slice; the rest run an
// independent edge task (FILL=false: histogram+rank; FILL=true: CSR fill).
// ---------------------------------------------------------------------------
template<int BM, int BN, int BK, int TN, bool FILL>
__global__ __launch_bounds__(256)
void gemm_edge_kernel(const float* __restrict__ A, const unsigned short* __restrict__ Bt,
                      unsigned short* __restrict__ C, int M, int K, int N,
                      int row_base, int gemm_blocks,
                      const int* __restrict__ src, const int* __restrict__ dst,
                      const float* __restrict__ ew, const int* __restrict__ rowptr,
                      const int* __restrict__ bsum,
                      int* __restrict__ cnt, int* __restrict__ rank,
                      int2* __restrict__ rec, int ne)
{
    __shared__ unsigned short As[BM * (BK + 8)];
    __shared__ unsigned short Bs[BN * (BK + 8)];

    if ((int)blockIdx.x >= gemm_blocks) {
        int e = ((int)blockIdx.x - gemm_blocks) * 256 + threadIdx.x;
        if (e < ne) {
            if constexpr (!FILL) {
                int rk = atomicAdd(&cnt[dst[e]], 1);
                __builtin_nontemporal_store(rk, &rank[e]);
            } else {
                int d = dst[e];
                int rk = __builtin_nontemporal_load(&rank[e]);
                int pos = rowptr[d] + bsum[d >> 8] + rk;
                rec[pos] = make_int2(src[e], __float_as_int(ew[e]));
            }
        }
        return;
    }
    gemm_tile<BM, BN, BK, TN>(As, Bs, A, Bt, C, M, K, N,
                              row_base + (int)blockIdx.x * BM);
}

// ---------------------------------------------------------------------------
// Merged dispatch: GEMM slice || scan1 (per-256-chunk exclusive scan of cnt;
// covers i <= n so rowptr[i]+bsum[i>>8] is the final prefix -- no scan3).
// ---------------------------------------------------------------------------
template<int BM, int BN, int BK, int TN>
__global__ __launch_bounds__(256)
void gemm_scan_kernel(const float* __restrict__ A, const unsigned short* __restrict__ Bt,
                      unsigned short* __restrict__ C, int M, int K, int N,
                      int row_base, int gemm_blocks,
                      const int* __restrict__ cnt, int* __restrict__ rowptr,
                      int* __restrict__ bsum, int n)
{
    __shared__ unsigned short As[BM * (BK + 8)];
    __shared__ unsigned short Bs[BN * (BK + 8)];

    if ((int)blockIdx.x >= gemm_blocks) {
        __shared__ int s[256];
        int blk = (int)blockIdx.x - gemm_blocks;
        int t = threadIdx.x;
        int i = blk * 256 + t;
        int v = (i <= n) ? cnt[i] : 0;
        s[t] = v;
        __syncthreads();
#pragma unroll
        for (int off = 1; off < 256; off <<= 1) {
            int x = (t >= off) ? s[t - off] : 0;
            __syncthreads();
            s[t] += x;
            __syncthreads();
        }
        if (i <= n) rowptr[i] = s[t] - v;
        if (t == 255) bsum[blk] = s[255];
        return;
    }
    gemm_tile<BM, BN, BK, TN>(As, Bs, A, Bt, C, M, K, N,
                              row_base + (int)blockIdx.x * BM);
}

__global__ __launch_bounds__(512)
void scan2_kernel(int* __restrict__ bsum, int nb)
{
    __shared__ int s[512];
    int t = threadIdx.x;
    int v = (t < nb) ? bsum[t] : 0;
    s[t] = v;
    __syncthreads();
#pragma unroll
    for (int off = 1; off < 512; off <<= 1) {
        int x = (t >= off) ? s[t - off] : 0;
        __syncthreads();
        s[t] += x;
        __syncthreads();
    }
    if (t < nb) bsum[t] = s[t] - v;
}

// ---------------------------------------------------------------------------
// Fused aggregation layer 1 + gemm2: 16 nodes/block, 4 waves.
// Each wave: 2 iterations x 2 nodes (32-lane halves, 4 feats/lane via uint2).
// rec read non-temporally (streamed once); h stored non-temporally (write-only
// output) -- keeps L2 for the gather-hot sup rows.
// Then per-wave h@W2 (16-col slab) via 4 MFMAs from the LDS bf16 h tile.
// ---------------------------------------------------------------------------
__global__ __launch_bounds__(256)
void agg1_fused_kernel(const unsigned int* __restrict__ sup, const int2* __restrict__ rec,
                       const int* __restrict__ rowptr, const int* __restrict__ bsum,
                       const float* __restrict__ b1,
                       const unsigned short* __restrict__ W2t,
                       float* __restrict__ h, unsigned short* __restrict__ sup2, int n)
{
    constexpr int LDH = F1 + 8;                 // 136 shorts = 272 B
    __shared__ unsigned short hsb[16 * LDH];    // 4.25 KB

    const long long* recq = (const long long*)rec;

    const int tid  = threadIdx.x;
    const int w    = tid >> 6;
    const int lane = tid & 63;
    const int half = lane >> 5;
    const int sl   = lane & 31;
    const int base = blockIdx.x * 16;

    f32x4 bb = *(const f32x4*)(b1 + sl * 4);

#pragma unroll
    for (int it = 0; it < 2; it++) {
        int row  = w * 4 + it * 2 + half;
        int node = base + row;
        f32x4 acc = (f32x4)0.f;
        if (node < n) {
            int j   = rowptr[node]     + bsum[node >> 8];
            int end = rowptr[node + 1] + bsum[(node + 1) >> 8];
            for (; j + 8 <= end; j += 8) {
                long long r[8];
#pragma unroll
                for (int u = 0; u < 8; u++) r[u] = __builtin_nontemporal_load(&recq[j + u]);
                uint2 uu[8];
#pragma unroll
                for (int u = 0; u < 8; u++)
                    uu[u] = *(const uint2*)(&sup[(long long)(int)r[u] * 64 + sl * 2]);
#pragma unroll
                for (int u = 0; u < 8; u++) {
                    float2 fa = h2f2(uu[u].x);
                    float2 fb = h2f2(uu[u].y);
                    float  ww = __int_as_float((int)(r[u] >> 32));
                    acc.x = fmaf(fa.x, ww, acc.x);
                    acc.y = fmaf(fa.y, ww, acc.y);
                    acc.z = fmaf(fb.x, ww, acc.z);
                    acc.w = fmaf(fb.y, ww, acc.w);
                }
            }
            for (; j < end; j++) {
                long long r0 = __builtin_nontemporal_load(&recq[j]);
                uint2 u0 = *(const uint2*)(&sup[(long long)(int)r0 * 64 + sl * 2]);
                float2 fa = h2f2(u0.x);
                float2 fb = h2f2(u0.y);
                float  ww = __int_as_float((int)(r0 >> 32));
                acc.x = fmaf(fa.x, ww, acc.x);
                acc.y = fmaf(fa.y, ww, acc.y);
                acc.z = fmaf(fb.x, ww, acc.z);
                acc.w = fmaf(fb.y, ww, acc.w);
            }
            acc.x += bb.x;  acc.y += bb.y;  acc.z += bb.z;  acc.w += bb.w;
            acc.x = acc.x > 0.f ? acc.x : 0.01f * acc.x;
            acc.y = acc.y > 0.f ? acc.y : 0.01f * acc.y;
            acc.z = acc.z > 0.f ? acc.z : 0.01f * acc.z;
            acc.w = acc.w > 0.f ? acc.w : 0.01f * acc.w;
            __builtin_nontemporal_store(acc, (f32x4*)(h + (long long)node * 128 + sl * 4));
        }
        ushort4 hv = (node < n)
            ? make_ushort4(f2bf(acc.x), f2bf(acc.y), f2bf(acc.z), f2bf(acc.w))
            : make_ushort4(0, 0, 0, 0);
        *(ushort4*)(&hsb[row * LDH + sl * 4]) = hv;
    }
    __syncthreads();

    // --- h @ W2 for this block's 16 nodes; wave w -> cols [w*16, w*16+16) ---
    const int lr   = lane & 15;
    const int quad = lane >> 4;
    f32x4 acc2 = (f32x4)0.f;
#pragma unroll
    for (int kk = 0; kk < F1; kk += 32) {
        bf16x8 a = *(const bf16x8*)(&hsb[lr * LDH + kk + quad * 8]);
        bf16x8 b = *(const bf16x8*)(W2t + (w * 16 + lr) * F1 + kk + quad * 8);
        acc2 = __builtin_amdgcn_mfma_f32_16x16x32_bf16(a, b, acc2, 0, 0, 0);
    }
#pragma unroll
    for (int r = 0; r < 4; r++) {
        int node = base + quad * 4 + r;
        if (node < n)
            sup2[(long long)node * 64 + w * 16 + lr] = f2h(acc2[r]);
    }
}

// ---------------------------------------------------------------------------
// Fused aggregation layer 2 + softmax: 2 nodes/wave (32-lane halves),
// 2 feats/lane (uint). rec nt-load; out nt-store (write-only).
// Softmax reduced within each 32-lane half (offsets 16..1).
// ---------------------------------------------------------------------------
__global__ __launch_bounds__(256)
void agg2_kernel(const unsigned short* __restrict__ sup, const int2* __restrict__ rec,
                 const int* __restrict__ rowptr, const int* __restrict__ bsum,
                 const float* __restrict__ b2, float* __restrict__ out, int n)
{
    const long long* recq = (const long long*)rec;
    const int lane = threadIdx.x & 63;
    const int half = lane >> 5;
    const int sl   = lane & 31;
    const int node = blockIdx.x * 8 + (threadIdx.x >> 6) * 2 + half;
    if (node >= n) return;

    int j   = rowptr[node]     + bsum[node >> 8];
    int end = rowptr[node + 1] + bsum[(node + 1) >> 8];
    float2 acc = make_float2(0.f, 0.f);

    for (; j + 8 <= end; j += 8) {
        long long r[8];
#pragma unroll
        for (int u = 0; u < 8; u++) r[u] = __builtin_nontemporal_load(&recq[j + u]);
        unsigned int uu[8];
#pragma unroll
        for (int u = 0; u < 8; u++)
            uu[u] = *(const unsigned int*)(&sup[(long long)(int)r[u] * 64 + sl * 2]);
#pragma unroll
        for (int u = 0; u < 8; u++) {
            float2 f = h2f2(uu[u]);
            float  ww = __int_as_float((int)(r[u] >> 32));
            acc.x = fmaf(f.x, ww, acc.x);
            acc.y = fmaf(f.y, ww, acc.y);
        }
    }
    for (; j < end; j++) {
        long long r0 = __builtin_nontemporal_load(&recq[j]);
        unsigned int u0 = *(const unsigned int*)(&sup[(long long)(int)r0 * 64 + sl * 2]);
        float2 f = h2f2(u0);
        float  ww = __int_as_float((int)(r0 >> 32));
        acc.x = fmaf(f.x, ww, acc.x);
        acc.y = fmaf(f.y, ww, acc.y);
    }

    float2 bv = *(const float2*)(b2 + sl * 2);
    float2 v  = make_float2(acc.x + bv.x, acc.y + bv.y);
    float m = fmaxf(v.x, v.y);
#pragma unroll
    for (int off = 16; off; off >>= 1) m = fmaxf(m, __shfl_xor(m, off, 64));
    float2 e = make_float2(__expf(v.x - m), __expf(v.y - m));
    float s = e.x + e.y;
#pragma unroll
    for (int off = 16; off; off >>= 1) s += __shfl_xor(s, off, 64);
    float inv = 1.f / s;
    f32x2 r; r.x = e.x * inv; r.y = e.y * inv;
    __builtin_nontemporal_store(r, (f32x2*)(out + (long long)node * 64 + sl * 2));
}

// ---------------------------------------------------------------------------
extern "C" void kernel_launch(void* const* d_in, const int* in_sizes, int n_in,
                              void* d_out, int out_size, void* d_ws, size_t ws_size,
                              hipStream_t stream)
{
    const float* y   = (const float*)d_in[0];   // [NN, F0]
    const int*   src = (const int*)  d_in[1];   // [NE]
    const int*   dst = (const int*)  d_in[2];   // [NE]
    const float* ew  = (const float*)d_in[3];   // [NE]
    const float* W1  = (const float*)d_in[4];   // [F0, F1]
    const float* b1  = (const float*)d_in[5];   // [F1]
    const float* W2  = (const float*)d_in[6];   // [F1, F2]
    const float* b2  = (const float*)d_in[7];   // [F2]

    float* out     = (float*)d_out;
    float* softout = out;                              // [NN, F2]
    float* h       = out + (size_t)NN * F2;            // [NN, F1] embedding

    // ---- workspace layout (256B-aligned chunks; total ~58.6 MB) ----
    char* ws = (char*)d_ws;
    size_t o = 0;
    auto alloc = [&](size_t bytes) -> void* {
        void* p = ws + o;
        o = (o + bytes + 255) & ~(size_t)255;
        return p;
    };
    unsigned short* sup  = (unsigned short*)alloc((size_t)NN * F1 * 2); // fp16 layer-1 support
    unsigned short* sup2 = (unsigned short*)alloc((size_t)NN * F2 * 2); // fp16 layer-2 support
    int2*           rec  = (int2*)          alloc((size_t)NE * 8);
    int*            rank = (int*)           alloc((size_t)NE * 4);
    int*            rowptr = (int*)         alloc((size_t)(NN + 2) * 4);
    int*            cnt  = (int*)           alloc((size_t)(NN + 256) * 4);
    int*            bsum = (int*)           alloc(512 * 4);
    unsigned short* W1t  = (unsigned short*)alloc((size_t)F0 * F1 * 2);
    unsigned short* W2t  = (unsigned short*)alloc((size_t)F1 * F2 * 2);

    const int NB = (NN + 255) / 256;          // 391 scan blocks (covers NN+1 items)
    const int GB = (NN + 127) / 128;          // 782 gemm1 blocks total
    const int GA = 312;                       // slice 1 (with hist)
    const int GS = 64;                        // slice 2 (with scan1)
    const int GC = GB - GA - GS;              // slice 3 (with fill) = 406
    const int EB = (NE + 255) / 256;          // 6250 edge blocks

    // ---- weights transpose + cnt zero (one launch, 391 blocks) ----
    wt_kernel<<<NB, 256, 0, stream>>>(W1, W2, W1t, W2t, cnt, NB * 256);

    // ---- [gemm1 slice 1 || histogram+rank] ----
    gemm_edge_kernel<128, 128, 64, 8, false><<<GA + EB, 256, 0, stream>>>(
        y, W1t, sup, NN, F0, F1, /*row_base=*/0, /*gemm_blocks=*/GA,
        src, dst, ew, rowptr, bsum, cnt, rank, rec, NE);

    // ---- [gemm1 slice 2 || scan1] ----
    gemm_scan_kernel<128, 128, 64, 8><<<GS + NB, 256, 0, stream>>>(
        y, W1t, sup, NN, F0, F1, /*row_base=*/GA * 128, /*gemm_blocks=*/GS,
        cnt, rowptr, bsum, NN);

    // ---- scan2 (tiny) ----
    scan2_kernel<<<1, 512, 0, stream>>>(bsum, NB);

    // ---- [gemm1 slice 3 || CSR fill] ----
    gemm_edge_kernel<128, 128, 64, 8, true><<<GC + EB, 256, 0, stream>>>(
        y, W1t, sup, NN, F0, F1, /*row_base=*/(GA + GS) * 128, /*gemm_blocks=*/GC,
        src, dst, ew, rowptr, bsum, cnt, rank, rec, NE);

    // ---- fused: gather-agg + bias + leaky-relu -> h; h @ W2 -> sup2 ----
    agg1_fused_kernel<<<(NN + 15) / 16, 256, 0, stream>>>(
        (const unsigned int*)sup, rec, rowptr, bsum, b1, W2t, h, sup2, NN);

    // ---- layer 2 aggregation + softmax ----
    agg2_kernel<<<(NN + 7) / 8, 256, 0, stream>>>(
        sup2, rec, rowptr, bsum, b2, softout, NN);
}

// Round 9
// 542.293 us; speedup vs baseline: 1.1218x; 1.1218x over previous
//
#include <hip/hip_runtime.h>
#include <hip/hip_fp16.h>

#define NN 100000      // nodes
#define NE 1600000     // edges
#define F0 512         // NFEAT
#define F1 128         // NHID
#define F2 64          // NCLASS

typedef short bf16x8 __attribute__((ext_vector_type(8)));
typedef float f32x4  __attribute__((ext_vector_type(4)));
typedef float f32x2  __attribute__((ext_vector_type(2)));

// fp32 -> bf16 (round-to-nearest-even, finite inputs)
static __device__ __forceinline__ unsigned short f2bf(float f) {
    unsigned int u = __float_as_uint(f);
    return (unsigned short)((u + 0x7FFFu + ((u >> 16) & 1u)) >> 16);
}

// fp32 -> fp16 bits (RNE)
static __device__ __forceinline__ unsigned short f2h(float f) {
    __half h = __float2half(f);
    return *(unsigned short*)&h;
}

// packed 2xfp16 -> 2xfp32
static __device__ __forceinline__ float2 h2f2(unsigned int u) {
    __half2 h = *(__half2*)&u;
    return __half22float2(h);
}

// ---------------------------------------------------------------------------
// Weights transpose+convert AND cnt zeroing in one launch (391 blocks).
// ---------------------------------------------------------------------------
__global__ __launch_bounds__(256)
void wt_kernel(const float* __restrict__ W1, const float* __restrict__ W2,
               unsigned short* __restrict__ W1t, unsigned short* __restrict__ W2t,
               int* __restrict__ cnt, int grid_threads)
{
    int i = blockIdx.x * 256 + threadIdx.x;
    if (i < F0 * F1) {
        int n = i / F0, k = i % F0;
        W1t[i] = f2bf(W1[k * F1 + n]);
    } else {
        int j = i - F0 * F1;
        if (j < F1 * F2) {
            int n = j / F1, k = j % F1;
            W2t[j] = f2bf(W2[k * F2 + n]);
        }
    }
    for (int z = i; z < NN + 256; z += grid_threads) cnt[z] = 0;
}

// ---------------------------------------------------------------------------
// Merged dispatch: blocks [0, gemm_blocks) run a slice of the bf16 MFMA GEMM;
// blocks [gemm_blocks, ...) run an independent edge task:
//   FILL=false: rank[e] = atomicAdd(&cnt[dst[e]], 1)                (histogram)
//   FILL=true : rec[rowptr[d]+bsum[d>>8]+rank[e]] = {src,w}         (CSR fill)
// A (y) tiles are nt-loaded: each line is read exactly once, so keep the
// 204.8 MB stream out of L2 (protects cnt atomics + gather-hot data).
// ---------------------------------------------------------------------------
template<int BM, int BN, int BK, int TN, bool FILL>
__global__ __launch_bounds__(256)
void gemm_edge_kernel(const float* __restrict__ A, const unsigned short* __restrict__ Bt,
                      unsigned short* __restrict__ C, int M, int K, int N,
                      int row_base, int gemm_blocks,
                      const int* __restrict__ src, const int* __restrict__ dst,
                      const float* __restrict__ ew, const int* __restrict__ rowptr,
                      const int* __restrict__ bsum,
                      int* __restrict__ cnt, int* __restrict__ rank,
                      int2* __restrict__ rec, int ne)
{
    constexpr int LDA = BK + 8;   // pad: 72 shorts = 144 B = 36 banks
    constexpr int LDB = BK + 8;
    __shared__ unsigned short As[BM * LDA];
    __shared__ unsigned short Bs[BN * LDB];

    if ((int)blockIdx.x >= gemm_blocks) {
        // ---- edge task ----
        int e = ((int)blockIdx.x - gemm_blocks) * 256 + threadIdx.x;
        if (e < ne) {
            if constexpr (!FILL) {
                rank[e] = atomicAdd(&cnt[dst[e]], 1);
            } else {
                int d = dst[e];
                int pos = rowptr[d] + bsum[d >> 8] + rank[e];
                rec[pos] = make_int2(src[e], __float_as_int(ew[e]));
            }
        }
        return;
    }

    // ---- GEMM slice ----
    const int tid  = threadIdx.x;
    const int wave = tid >> 6;
    const int lane = tid & 63;
    const int lr   = lane & 15;
    const int quad = lane >> 4;
    const int row0 = row_base + (int)blockIdx.x * BM;

    f32x4 acc[2][TN];
#pragma unroll
    for (int i = 0; i < 2; i++)
#pragma unroll
        for (int j = 0; j < TN; j++) acc[i][j] = (f32x4)0.f;

    for (int k0 = 0; k0 < K; k0 += BK) {
        // --- stage A tile (BM x BK) fp32 -> bf16 (nt: single-use stream) ---
#pragma unroll
        for (int l = tid; l < BM * (BK / 4); l += 256) {
            int m  = l / (BK / 4);
            int kq = l % (BK / 4);
            int rg = row0 + m; if (rg >= M) rg = M - 1;
            f32x4 v = __builtin_nontemporal_load(
                (const f32x4*)(A + (long long)rg * K + k0 + kq * 4));
            ushort4 b = make_ushort4(f2bf(v.x), f2bf(v.y), f2bf(v.z), f2bf(v.w));
            *(ushort4*)(&As[m * LDA + kq * 4]) = b;
        }
        // --- stage B tile (BN x BK) from Bt[N,K] (already bf16) ---
#pragma unroll
        for (int l = tid; l < BN * (BK / 8); l += 256) {
            int n  = l / (BK / 8);
            int ko = l % (BK / 8);
            uint4 v = *(const uint4*)(Bt + (long long)n * K + k0 + ko * 8);
            *(uint4*)(&Bs[n * LDB + ko * 8]) = v;
        }
        __syncthreads();

#pragma unroll
        for (int kk = 0; kk < BK; kk += 32) {
            bf16x8 a[2], b[TN];
#pragma unroll
            for (int tm = 0; tm < 2; tm++)
                a[tm] = *(const bf16x8*)(&As[(wave * 32 + tm * 16 + lr) * LDA + kk + quad * 8]);
#pragma unroll
            for (int tn = 0; tn < TN; tn++)
                b[tn] = *(const bf16x8*)(&Bs[(tn * 16 + lr) * LDB + kk + quad * 8]);
#pragma unroll
            for (int tm = 0; tm < 2; tm++)
#pragma unroll
                for (int tn = 0; tn < TN; tn++)
                    acc[tm][tn] = __builtin_amdgcn_mfma_f32_16x16x32_bf16(
                        a[tm], b[tn], acc[tm][tn], 0, 0, 0);
        }
        __syncthreads();
    }

    // --- epilogue: C/D layout col=lane&15, row=quad*4+reg; store fp16 ---
#pragma unroll
    for (int tm = 0; tm < 2; tm++) {
#pragma unroll
        for (int r = 0; r < 4; r++) {
            int row = row0 + wave * 32 + tm * 16 + quad * 4 + r;
            if (row < M) {
#pragma unroll
                for (int tn = 0; tn < TN; tn++)
                    C[(long long)row * N + tn * 16 + lr] = f2h(acc[tm][tn][r]);
            }
        }
    }
}

// ---------------------------------------------------------------------------
// CSR scan: scan1 covers i <= n (cnt[NN]=0), so rowptr[i]+bsum[i>>8] is the
// final exclusive prefix for ALL i in [0, NN] -- no scan3 pass needed.
// ---------------------------------------------------------------------------
__global__ __launch_bounds__(256)
void scan1_kernel(const int* __restrict__ cnt, int* __restrict__ rowptr,
                  int* __restrict__ bsum, int n)
{
    __shared__ int s[256];
    int t = threadIdx.x;
    int i = blockIdx.x * 256 + t;
    int v = (i <= n) ? cnt[i] : 0;
    s[t] = v;
    __syncthreads();
#pragma unroll
    for (int off = 1; off < 256; off <<= 1) {
        int x = (t >= off) ? s[t - off] : 0;
        __syncthreads();
        s[t] += x;
        __syncthreads();
    }
    if (i <= n) rowptr[i] = s[t] - v;
    if (t == 255) bsum[blockIdx.x] = s[255];
}

__global__ __launch_bounds__(512)
void scan2_kernel(int* __restrict__ bsum, int nb)
{
    __shared__ int s[512];
    int t = threadIdx.x;
    int v = (t < nb) ? bsum[t] : 0;
    s[t] = v;
    __syncthreads();
#pragma unroll
    for (int off = 1; off < 512; off <<= 1) {
        int x = (t >= off) ? s[t - off] : 0;
        __syncthreads();
        s[t] += x;
        __syncthreads();
    }
    if (t < nb) bsum[t] = s[t] - v;
}

// ---------------------------------------------------------------------------
// Fused aggregation layer 1 + gemm2: 16 nodes/block, 4 waves.
// Each wave: 2 iterations x 2 nodes (32-lane halves, 4 feats/lane via uint2).
// h stored non-temporally (write-only output; keep 51.2 MB out of L2).
// Then per-wave h@W2 (16-col slab) via 4 MFMAs from the LDS bf16 h tile.
// ---------------------------------------------------------------------------
__global__ __launch_bounds__(256)
void agg1_fused_kernel(const unsigned int* __restrict__ sup, const int2* __restrict__ rec,
                       const int* __restrict__ rowptr, const int* __restrict__ bsum,
                       const float* __restrict__ b1,
                       const unsigned short* __restrict__ W2t,
                       float* __restrict__ h, unsigned short* __restrict__ sup2, int n)
{
    constexpr int LDH = F1 + 8;                 // 136 shorts = 272 B
    __shared__ unsigned short hsb[16 * LDH];    // 4.25 KB

    const int tid  = threadIdx.x;
    const int w    = tid >> 6;
    const int lane = tid & 63;
    const int half = lane >> 5;
    const int sl   = lane & 31;
    const int base = blockIdx.x * 16;

    float4 bb = *(const float4*)(b1 + sl * 4);

#pragma unroll
    for (int it = 0; it < 2; it++) {
        int row  = w * 4 + it * 2 + half;
        int node = base + row;
        f32x4 acc = (f32x4)0.f;
        if (node < n) {
            int j   = rowptr[node]     + bsum[node >> 8];
            int end = rowptr[node + 1] + bsum[(node + 1) >> 8];
            for (; j + 8 <= end; j += 8) {
                int2 r[8];
#pragma unroll
                for (int u = 0; u < 8; u++) r[u] = rec[j + u];
                uint2 uu[8];
#pragma unroll
                for (int u = 0; u < 8; u++)
                    uu[u] = *(const uint2*)(&sup[(long long)r[u].x * 64 + sl * 2]);
#pragma unroll
                for (int u = 0; u < 8; u++) {
                    float2 fa = h2f2(uu[u].x);
                    float2 fb = h2f2(uu[u].y);
                    float  ww = __int_as_float(r[u].y);
                    acc.x = fmaf(fa.x, ww, acc.x);
                    acc.y = fmaf(fa.y, ww, acc.y);
                    acc.z = fmaf(fb.x, ww, acc.z);
                    acc.w = fmaf(fb.y, ww, acc.w);
                }
            }
            for (; j < end; j++) {
                int2 r0 = rec[j];
                uint2 u0 = *(const uint2*)(&sup[(long long)r0.x * 64 + sl * 2]);
                float2 fa = h2f2(u0.x);
                float2 fb = h2f2(u0.y);
                float  ww = __int_as_float(r0.y);
                acc.x = fmaf(fa.x, ww, acc.x);
                acc.y = fmaf(fa.y, ww, acc.y);
                acc.z = fmaf(fb.x, ww, acc.z);
                acc.w = fmaf(fb.y, ww, acc.w);
            }
            acc.x += bb.x;  acc.y += bb.y;  acc.z += bb.z;  acc.w += bb.w;
            acc.x = acc.x > 0.f ? acc.x : 0.01f * acc.x;
            acc.y = acc.y > 0.f ? acc.y : 0.01f * acc.y;
            acc.z = acc.z > 0.f ? acc.z : 0.01f * acc.z;
            acc.w = acc.w > 0.f ? acc.w : 0.01f * acc.w;
            __builtin_nontemporal_store(acc, (f32x4*)(h + (long long)node * 128 + sl * 4));
        }
        ushort4 hv = (node < n)
            ? make_ushort4(f2bf(acc.x), f2bf(acc.y), f2bf(acc.z), f2bf(acc.w))
            : make_ushort4(0, 0, 0, 0);
        *(ushort4*)(&hsb[row * LDH + sl * 4]) = hv;
    }
    __syncthreads();

    // --- h @ W2 for this block's 16 nodes; wave w -> cols [w*16, w*16+16) ---
    const int lr   = lane & 15;
    const int quad = lane >> 4;
    f32x4 acc2 = (f32x4)0.f;
#pragma unroll
    for (int kk = 0; kk < F1; kk += 32) {
        bf16x8 a = *(const bf16x8*)(&hsb[lr * LDH + kk + quad * 8]);
        bf16x8 b = *(const bf16x8*)(W2t + (w * 16 + lr) * F1 + kk + quad * 8);
        acc2 = __builtin_amdgcn_mfma_f32_16x16x32_bf16(a, b, acc2, 0, 0, 0);
    }
#pragma unroll
    for (int r = 0; r < 4; r++) {
        int node = base + quad * 4 + r;
        if (node < n)
            sup2[(long long)node * 64 + w * 16 + lr] = f2h(acc2[r]);
    }
}

// ---------------------------------------------------------------------------
// Fused aggregation layer 2 + softmax: 2 nodes/wave (32-lane halves),
// 2 feats/lane (uint). out stored non-temporally (write-only output).
// Softmax reduced within each 32-lane half (offsets 16..1).
// ---------------------------------------------------------------------------
__global__ __launch_bounds__(256)
void agg2_kernel(const unsigned short* __restrict__ sup, const int2* __restrict__ rec,
                 const int* __restrict__ rowptr, const int* __restrict__ bsum,
                 const float* __restrict__ b2, float* __restrict__ out, int n)
{
    const int lane = threadIdx.x & 63;
    const int half = lane >> 5;
    const int sl   = lane & 31;
    const int node = blockIdx.x * 8 + (threadIdx.x >> 6) * 2 + half;
    if (node >= n) return;

    int j   = rowptr[node]     + bsum[node >> 8];
    int end = rowptr[node + 1] + bsum[(node + 1) >> 8];
    float2 acc = make_float2(0.f, 0.f);

    for (; j + 8 <= end; j += 8) {
        int2 r[8];
#pragma unroll
        for (int u = 0; u < 8; u++) r[u] = rec[j + u];
        unsigned int uu[8];
#pragma unroll
        for (int u = 0; u < 8; u++)
            uu[u] = *(const unsigned int*)(&sup[(long long)r[u].x * 64 + sl * 2]);
#pragma unroll
        for (int u = 0; u < 8; u++) {
            float2 f = h2f2(uu[u]);
            float  ww = __int_as_float(r[u].y);
            acc.x = fmaf(f.x, ww, acc.x);
            acc.y = fmaf(f.y, ww, acc.y);
        }
    }
    for (; j < end; j++) {
        int2 r0 = rec[j];
        unsigned int u0 = *(const unsigned int*)(&sup[(long long)r0.x * 64 + sl * 2]);
        float2 f = h2f2(u0);
        float  ww = __int_as_float(r0.y);
        acc.x = fmaf(f.x, ww, acc.x);
        acc.y = fmaf(f.y, ww, acc.y);
    }

    float2 bv = *(const float2*)(b2 + sl * 2);
    float2 v  = make_float2(acc.x + bv.x, acc.y + bv.y);
    float m = fmaxf(v.x, v.y);
#pragma unroll
    for (int off = 16; off; off >>= 1) m = fmaxf(m, __shfl_xor(m, off, 64));
    float2 e = make_float2(__expf(v.x - m), __expf(v.y - m));
    float s = e.x + e.y;
#pragma unroll
    for (int off = 16; off; off >>= 1) s += __shfl_xor(s, off, 64);
    float inv = 1.f / s;
    f32x2 r; r.x = e.x * inv; r.y = e.y * inv;
    __builtin_nontemporal_store(r, (f32x2*)(out + (long long)node * 64 + sl * 2));
}

// ---------------------------------------------------------------------------
extern "C" void kernel_launch(void* const* d_in, const int* in_sizes, int n_in,
                              void* d_out, int out_size, void* d_ws, size_t ws_size,
                              hipStream_t stream)
{
    const float* y   = (const float*)d_in[0];   // [NN, F0]
    const int*   src = (const int*)  d_in[1];   // [NE]
    const int*   dst = (const int*)  d_in[2];   // [NE]
    const float* ew  = (const float*)d_in[3];   // [NE]
    const float* W1  = (const float*)d_in[4];   // [F0, F1]
    const float* b1  = (const float*)d_in[5];   // [F1]
    const float* W2  = (const float*)d_in[6];   // [F1, F2]
    const float* b2  = (const float*)d_in[7];   // [F2]

    float* out     = (float*)d_out;
    float* softout = out;                              // [NN, F2]
    float* h       = out + (size_t)NN * F2;            // [NN, F1] embedding

    // ---- workspace layout (256B-aligned chunks; total ~58.6 MB) ----
    char* ws = (char*)d_ws;
    size_t o = 0;
    auto alloc = [&](size_t bytes) -> void* {
        void* p = ws + o;
        o = (o + bytes + 255) & ~(size_t)255;
        return p;
    };
    unsigned short* sup  = (unsigned short*)alloc((size_t)NN * F1 * 2); // fp16 layer-1 support
    unsigned short* sup2 = (unsigned short*)alloc((size_t)NN * F2 * 2); // fp16 layer-2 support
    int2*           rec  = (int2*)          alloc((size_t)NE * 8);
    int*            rank = (int*)           alloc((size_t)NE * 4);
    int*            rowptr = (int*)         alloc((size_t)(NN + 2) * 4);
    int*            cnt  = (int*)           alloc((size_t)(NN + 256) * 4);
    int*            bsum = (int*)           alloc(512 * 4);
    unsigned short* W1t  = (unsigned short*)alloc((size_t)F0 * F1 * 2);
    unsigned short* W2t  = (unsigned short*)alloc((size_t)F1 * F2 * 2);

    const int NB = (NN + 255) / 256;          // 391 scan blocks
    const int GB = (NN + 127) / 128;          // 782 gemm1 blocks total
    const int GA = 312;                       // first-half blocks (rebalanced)
    const int EB = (NE + 255) / 256;          // 6250 edge blocks

    // ---- weights transpose + cnt zero (one launch, 391 blocks) ----
    wt_kernel<<<NB, 256, 0, stream>>>(W1, W2, W1t, W2t, cnt, NB * 256);

    // ---- [gemm1 first slice || histogram+rank] ----
    gemm_edge_kernel<128, 128, 64, 8, false><<<GA + EB, 256, 0, stream>>>(
        y, W1t, sup, NN, F0, F1, /*row_base=*/0, /*gemm_blocks=*/GA,
        src, dst, ew, rowptr, bsum, cnt, rank, rec, NE);

    // ---- CSR scan (2 kernels; scan3 folded into consumers) ----
    scan1_kernel<<<NB, 256, 0, stream>>>(cnt, rowptr, bsum, NN);
    scan2_kernel<<<1, 512, 0, stream>>>(bsum, NB);

    // ---- [gemm1 second slice || CSR fill] ----
    gemm_edge_kernel<128, 128, 64, 8, true><<<(GB - GA) + EB, 256, 0, stream>>>(
        y, W1t, sup, NN, F0, F1, /*row_base=*/GA * 128, /*gemm_blocks=*/GB - GA,
        src, dst, ew, rowptr, bsum, cnt, rank, rec, NE);

    // ---- fused: gather-agg + bias + leaky-relu -> h; h @ W2 -> sup2 ----
    agg1_fused_kernel<<<(NN + 15) / 16, 256, 0, stream>>>(
        (const unsigned int*)sup, rec, rowptr, bsum, b1, W2t, h, sup2, NN);

    // ---- layer 2 aggregation + softmax ----
    agg2_kernel<<<(NN + 7) / 8, 256, 0, stream>>>(
        sup2, rec, rowptr, bsum, b2, softout, NN);
}